// Round 6
// baseline (2877.327 us; speedup 1.0000x reference)
//
#include <hip/hip_runtime.h>
#include <stdint.h>

typedef unsigned short u16;
typedef short bf16x8 __attribute__((ext_vector_type(8)));
typedef float f32x4 __attribute__((ext_vector_type(4)));

#define B_   4
#define S_   2048
#define D_   1024
#define ND3  3072

// RNE float->bf16
__device__ __forceinline__ u16 f2bf(float x) {
    union { float f; uint32_t u; } v; v.f = x;
    uint32_t r = v.u + 0x7fffu + ((v.u >> 16) & 1u);
    return (u16)(r >> 16);
}
__device__ __forceinline__ float bf2f(u16 h) {
    union { uint32_t u; float f; } v; v.u = ((uint32_t)h) << 16;
    return v.f;
}

__device__ __forceinline__ void gload_lds16(const u16* g, u16* l) {
    __builtin_amdgcn_global_load_lds((const __attribute__((address_space(1))) void*)g,
                                     (__attribute__((address_space(3))) void*)l, 16, 0, 0);
}

// bijective XCD swizzle for nwg % 8 == 0
__device__ __forceinline__ int xcd_swz(int lid, int nwg) {
    int c = nwg >> 3;
    return (lid & 7) * c + (lid >> 3);
}

// ================= 256x256 bf16 GEMM core, K-step=32 double-buffer =================
// acc += sum_s A_s @ B_s^T over NSEG segments, each K = NTSEG*64 (steps of 32).
// 512 threads = 8 waves (2Mrow x 4Ncol), per-wave output 128x64.
// LDS 64KB: A [2 slots][256r][32k] + B [2 slots][256r][32k]; slot = step & 1.
// Swizzle: logical chunk c (16B) of row r stored at c ^ ((r>>1)&3); applied on
// the global SOURCE address (linear LDS dest) and identically on ds_read.
// Race-free schedule per step S:
//   lgkmcnt(0)            -- own reads of slot (S-1)&1 drained
//   barrier               -- ALL waves drained slot (S+1)&1's previous readers
//   ISSUE(S+1)            -- 4 loads into slot (S+1)&1 (safe: just drained)
//   vmcnt(4)              -- own step-S loads landed (S+1's 4 still in flight)
//   barrier               -- all waves' step-S loads landed
//   body: 12 ds_read_b128 + 32 MFMA, no fences (compiler inserts lgkmcnt)
// Writes to a slot always follow a barrier that followed the lgkm-drain of all
// of that slot's readers => no read/write race. Prefetch distance = 1 body.
template<int NSEG, int NTSEG>
__device__ __forceinline__ void gemm256(const u16* __restrict__ a0, const u16* __restrict__ b0,
                                        const u16* __restrict__ a1, const u16* __restrict__ b1,
                                        const u16* __restrict__ a2, const u16* __restrict__ b2,
                                        int lda, int ldb, int rowbase, int colbase,
                                        u16* ldsA, u16* ldsB, f32x4 (&acc)[8][4])
{
    const int NSTEP = 2 * NSEG * NTSEG;
    const int tid  = threadIdx.x;
    const int lane = tid & 63;
    const int w    = tid >> 6;
    const int wr   = w >> 2, wc = w & 3;

    // staging: thread tid -> row r0 = tid>>2 (and r0+128), physical chunk tid&3
    // (linear dest), global source chunk = (tid&3) ^ ((r0>>1)&3)
    const int r0 = tid >> 2;
    const int c0 = (((tid & 3) ^ ((tid >> 3) & 3)) << 3);
    const size_t offA0 = (size_t)(rowbase + r0) * lda + c0;
    const size_t offA1 = offA0 + (size_t)128 * lda;
    const size_t offB0 = (size_t)(colbase + r0) * ldb + c0;
    const size_t offB1 = offB0 + (size_t)128 * ldb;
    const int dst0 = tid << 3;            // u16 units within 8192-u16 slot
    const int dst1 = 4096 + (tid << 3);

    // ds_read per-lane: row = fragbase + (lane&15), logical chunk = lane>>4,
    // physical chunk = (lane>>4) ^ ((row>>1)&3)
    const int rd_lane = ((lane & 15) << 5) + ((((lane >> 4) ^ (lane >> 1)) & 3) << 3);
    const int wrOff = wr << 12;           // wr*128 rows * 32 u16
    const int wcOff = wc << 11;           // wc*64 rows * 32 u16

#define ISSUE(sv) do { int s_ = (sv); \
    if (s_ < NSTEP) { \
        int local_ = s_ & (2 * NTSEG - 1); \
        const u16* Ab_; const u16* Bb_; \
        if (NSEG == 1) { Ab_ = a0; Bb_ = b0; } \
        else { int seg_ = s_ / (2 * NTSEG); \
               Ab_ = seg_ == 0 ? a0 : (seg_ == 1 ? a1 : a2); \
               Bb_ = seg_ == 0 ? b0 : (seg_ == 1 ? b1 : b2); } \
        size_t ko_ = (size_t)local_ << 5; \
        int sl_ = (s_ & 1) << 13; \
        gload_lds16(Ab_ + offA0 + ko_, ldsA + sl_ + dst0); \
        gload_lds16(Ab_ + offA1 + ko_, ldsA + sl_ + dst1); \
        gload_lds16(Bb_ + offB0 + ko_, ldsB + sl_ + dst0); \
        gload_lds16(Bb_ + offB1 + ko_, ldsB + sl_ + dst1); \
    } } while (0)

    bf16x8 af[4], bf[4];

#define LDA4(sl, mh) { _Pragma("unroll") for (int mq = 0; mq < 4; ++mq) \
    af[mq] = *(const bf16x8*)(ldsA + (sl) + wrOff + ((mh) << 11) + (mq << 9) + rd_lane); }
#define LDB4(sl) { _Pragma("unroll") for (int n = 0; n < 4; ++n) \
    bf[n] = *(const bf16x8*)(ldsB + (sl) + wcOff + (n << 9) + rd_lane); }
#define MFMA16(mh) { __builtin_amdgcn_s_setprio(1); \
    _Pragma("unroll") for (int mq = 0; mq < 4; ++mq) \
    _Pragma("unroll") for (int n = 0; n < 4; ++n) \
        acc[(mh) * 4 + mq][n] = __builtin_amdgcn_mfma_f32_16x16x32_bf16(af[mq], bf[n], acc[(mh) * 4 + mq][n], 0, 0, 0); \
    __builtin_amdgcn_s_setprio(0); }

#define STEP(sv, sl) { \
    asm volatile("s_waitcnt lgkmcnt(0)" ::: "memory"); \
    __builtin_amdgcn_s_barrier(); \
    asm volatile("" ::: "memory"); \
    ISSUE((sv) + 1); \
    if ((sv) < NSTEP - 1) asm volatile("s_waitcnt vmcnt(4)" ::: "memory"); \
    else                  asm volatile("s_waitcnt vmcnt(0)" ::: "memory"); \
    __builtin_amdgcn_s_barrier(); \
    asm volatile("" ::: "memory"); \
    LDA4(sl, 0); LDB4(sl); \
    MFMA16(0); \
    LDA4(sl, 1); \
    MFMA16(1); }

    ISSUE(0);
    for (int T = 0; T < NSEG * NTSEG; ++T) {
        STEP(2 * T,     0)
        STEP(2 * T + 1, 8192)
    }
#undef STEP
#undef MFMA16
#undef LDB4
#undef LDA4
#undef ISSUE
}

// ---------------- stage 0a: fp32 -> (hi, lo) bf16 split ----------------
__global__ __launch_bounds__(256) void k_split_f32(const float* __restrict__ in,
                                                   u16* __restrict__ oh,
                                                   u16* __restrict__ ol, int n) {
    int i = (blockIdx.x * 256 + threadIdx.x) << 3;
    if (i >= n) return;
    float4 a = *(const float4*)(in + i);
    float4 b = *(const float4*)(in + i + 4);
    ushort4 h0, h1, l0, l1;
    h0.x = f2bf(a.x); l0.x = f2bf(a.x - bf2f(h0.x));
    h0.y = f2bf(a.y); l0.y = f2bf(a.y - bf2f(h0.y));
    h0.z = f2bf(a.z); l0.z = f2bf(a.z - bf2f(h0.z));
    h0.w = f2bf(a.w); l0.w = f2bf(a.w - bf2f(h0.w));
    h1.x = f2bf(b.x); l1.x = f2bf(b.x - bf2f(h1.x));
    h1.y = f2bf(b.y); l1.y = f2bf(b.y - bf2f(h1.y));
    h1.z = f2bf(b.z); l1.z = f2bf(b.z - bf2f(h1.z));
    h1.w = f2bf(b.w); l1.w = f2bf(b.w - bf2f(h1.w));
    *(ushort4*)(oh + i)     = h0;
    *(ushort4*)(oh + i + 4) = h1;
    *(ushort4*)(ol + i)     = l0;
    *(ushort4*)(ol + i + 4) = l1;
}

// ---------------- stage 0b: W [R][C] fp32 -> Wt hi/lo [C][R] bf16 ----------------
__global__ __launch_bounds__(256) void k_transpose_split(const float* __restrict__ W,
                                                         u16* __restrict__ Wth,
                                                         u16* __restrict__ Wtl, int R, int C) {
    __shared__ float t[32][33];
    int tx = threadIdx.x & 31, ty = threadIdx.x >> 5;
    int c0 = blockIdx.x << 5, r0 = blockIdx.y << 5;
#pragma unroll
    for (int i = 0; i < 4; ++i) {
        int r = (i << 3) + ty;
        t[r][tx] = W[(size_t)(r0 + r) * C + c0 + tx];
    }
    __syncthreads();
#pragma unroll
    for (int i = 0; i < 4; ++i) {
        int r = (i << 3) + ty;
        float w = t[tx][r];
        u16 h = f2bf(w);
        Wth[(size_t)(c0 + r) * R + r0 + tx] = h;
        Wtl[(size_t)(c0 + r) * R + r0 + tx] = f2bf(w - bf2f(h));
    }
}

// ---------------- stage 1: QKV (hi/lo 3-seg fused); split-store q,k; v transposed ----------------
__global__ __launch_bounds__(512, 4) void k_qkv(const u16* __restrict__ xh,
                                                const u16* __restrict__ xl,
                                                const u16* __restrict__ wth,
                                                const u16* __restrict__ wtl,
                                                const float* __restrict__ bias,
                                                u16* __restrict__ qhi, u16* __restrict__ qlo,
                                                u16* __restrict__ khi, u16* __restrict__ klo,
                                                u16* __restrict__ vt) {
    __shared__ u16 lds[32768];
    f32x4 acc[8][4];
    f32x4 z = {0.f, 0.f, 0.f, 0.f};
#pragma unroll
    for (int m = 0; m < 8; ++m)
#pragma unroll
        for (int n = 0; n < 4; ++n) acc[m][n] = z;

    // T1 bijective XCD swizzle over 12x32 = 384 wgs
    const int lid = blockIdx.y * 12 + blockIdx.x;
    const int swz = xcd_swz(lid, 384);
    const int bx = swz % 12, by = swz / 12;
    const int rowbase = by << 8;
    const int colbase = bx << 8;
    gemm256<3, 16>(xh, wth, xh, wtl, xl, wth, D_, D_, rowbase, colbase,
                   lds, lds + 16384, acc);

    const int lane = threadIdx.x & 63;
    const int w = threadIdx.x >> 6;
    const int wr = w >> 2, wc = w & 3;
    const int region = colbase >> 10;   // 0=q, 1=k, 2=v (256 | 1024)
#pragma unroll
    for (int m = 0; m < 8; ++m) {
        int gr0 = rowbase + wr * 128 + m * 16 + ((lane >> 4) << 2);
#pragma unroll
        for (int n = 0; n < 4; ++n) {
            int gc = colbase + wc * 64 + n * 16 + (lane & 15);
            float bv = bias[gc];
            if (region == 0) {
#pragma unroll
                for (int r = 0; r < 4; ++r) {
                    float val = acc[m][n][r] + bv;
                    u16 h = f2bf(val);
                    size_t idx = (size_t)(gr0 + r) * D_ + gc;
                    qhi[idx] = h;
                    qlo[idx] = f2bf(val - bf2f(h));
                }
            } else if (region == 1) {
                int c = gc - 1024;
#pragma unroll
                for (int r = 0; r < 4; ++r) {
                    float val = acc[m][n][r] + bv;
                    u16 h = f2bf(val);
                    size_t idx = (size_t)(gr0 + r) * D_ + c;
                    khi[idx] = h;
                    klo[idx] = f2bf(val - bf2f(h));
                }
            } else {
                int d  = gc - 2048;
                int b  = gr0 >> 11;
                int t0 = gr0 & 2047;
                size_t base = (((size_t)b << 10) + d) * (size_t)S_ + t0;
#pragma unroll
                for (int r = 0; r < 4; ++r)
                    vt[base + r] = f2bf(acc[m][n][r] + bv);
            }
        }
    }
}

// ---------------- stage 2: attn = sigmoid(32 * q @ k^T) (3-seg fused), bf16 ----------------
__global__ __launch_bounds__(512, 4) void k_scores(const u16* __restrict__ qhi,
                                                   const u16* __restrict__ qlo,
                                                   const u16* __restrict__ khi,
                                                   const u16* __restrict__ klo,
                                                   u16* __restrict__ attn) {
    __shared__ u16 lds[32768];
    f32x4 acc[8][4];
    f32x4 z = {0.f, 0.f, 0.f, 0.f};
#pragma unroll
    for (int m = 0; m < 8; ++m)
#pragma unroll
        for (int n = 0; n < 4; ++n) acc[m][n] = z;

    // swizzle over 8x8x4 = 256 wgs
    const int lid = (blockIdx.z << 6) + (blockIdx.y << 3) + blockIdx.x;
    const int swz = xcd_swz(lid, 256);
    const int bx = swz & 7, by = (swz >> 3) & 7, b = swz >> 6;

    const size_t boff = (size_t)b * S_ * D_;
    u16* att = attn + (size_t)b * S_ * S_;
    const int rowbase = by << 8, colbase = bx << 8;
    gemm256<3, 16>(qhi + boff, khi + boff, qhi + boff, klo + boff, qlo + boff, khi + boff,
                   D_, D_, rowbase, colbase, lds, lds + 16384, acc);

    const int lane = threadIdx.x & 63;
    const int w = threadIdx.x >> 6;
    const int wr = w >> 2, wc = w & 3;
#pragma unroll
    for (int m = 0; m < 8; ++m) {
        int gr0 = rowbase + wr * 128 + m * 16 + ((lane >> 4) << 2);
#pragma unroll
        for (int n = 0; n < 4; ++n) {
            int gc = colbase + wc * 64 + n * 16 + (lane & 15);
#pragma unroll
            for (int r = 0; r < 4; ++r) {
                float sv = acc[m][n][r] * 32.0f;
                float sg = 1.0f / (1.0f + __expf(-sv));
                att[(size_t)(gr0 + r) * S_ + gc] = f2bf(sg);
            }
        }
    }
}

// ---------------- stage 3: out = attn @ v  (Bt = v^T [D][S]) ----------------
__global__ __launch_bounds__(512, 4) void k_pv(const u16* __restrict__ attn,
                                               const u16* __restrict__ vt,
                                               float* __restrict__ out) {
    __shared__ u16 lds[32768];
    f32x4 acc[8][4];
    f32x4 z = {0.f, 0.f, 0.f, 0.f};
#pragma unroll
    for (int m = 0; m < 8; ++m)
#pragma unroll
        for (int n = 0; n < 4; ++n) acc[m][n] = z;

    // swizzle over 4x8x4 = 128 wgs
    const int lid = (blockIdx.z << 5) + (blockIdx.y << 2) + blockIdx.x;
    const int swz = xcd_swz(lid, 128);
    const int bx = swz & 3, by = (swz >> 2) & 7, b = swz >> 5;

    const u16* Aa = attn + (size_t)b * S_ * S_;
    const u16* Bv = vt   + (size_t)b * D_ * S_;
    float* ob     = out  + (size_t)b * S_ * D_;
    const int rowbase = by << 8, colbase = bx << 8;
    gemm256<1, 32>(Aa, Bv, Aa, Bv, Aa, Bv, S_, S_, rowbase, colbase,
                   lds, lds + 16384, acc);

    const int lane = threadIdx.x & 63;
    const int w = threadIdx.x >> 6;
    const int wr = w >> 2, wc = w & 3;
#pragma unroll
    for (int m = 0; m < 8; ++m) {
        int gr0 = rowbase + wr * 128 + m * 16 + ((lane >> 4) << 2);
#pragma unroll
        for (int n = 0; n < 4; ++n) {
            int gc = colbase + wc * 64 + n * 16 + (lane & 15);
#pragma unroll
            for (int r = 0; r < 4; ++r)
                ob[(size_t)(gr0 + r) * D_ + gc] = acc[m][n][r];
        }
    }
}

extern "C" void kernel_launch(void* const* d_in, const int* in_sizes, int n_in,
                              void* d_out, int out_size, void* d_ws, size_t ws_size,
                              hipStream_t stream) {
    const float* x    = (const float*)d_in[0];
    const float* wqkv = (const float*)d_in[1];
    const float* bias = (const float*)d_in[2];
    float* out = (float*)d_out;

    const size_t MB = 1048576;
    uint8_t* ws = (uint8_t*)d_ws;
    u16* xh   = (u16*)(ws);              // [8192][1024] bf16   16 MB
    u16* xl   = (u16*)(ws + 16 * MB);    // 16 MB
    u16* wth  = (u16*)(ws + 32 * MB);    // [3072][1024] bf16    6 MB
    u16* wtl  = (u16*)(ws + 38 * MB);    //  6 MB
    u16* qh   = (u16*)(ws + 44 * MB);    // [B][S][D] bf16      16 MB
    u16* ql   = (u16*)(ws + 60 * MB);    // 16 MB
    u16* kh   = (u16*)(ws + 76 * MB);    // 16 MB
    u16* kl   = (u16*)(ws + 92 * MB);    // 16 MB
    u16* vt   = (u16*)(ws + 108 * MB);   // [B][D][S] bf16      16 MB (ends 124 MB)
    u16* attn = (u16*)(ws);              // [B][S][S] bf16 32 MB — aliases xh/xl (dead after QKV)

    k_split_f32<<<dim3(4096), dim3(256), 0, stream>>>(x, xh, xl, B_ * S_ * D_);
    k_transpose_split<<<dim3(ND3 / 32, D_ / 32), dim3(256), 0, stream>>>(wqkv, wth, wtl, D_, ND3);
    k_qkv<<<dim3(ND3 / 256, (B_ * S_) / 256), dim3(512), 0, stream>>>(xh, xl, wth, wtl, bias,
                                                                      qh, ql, kh, kl, vt);
    k_scores<<<dim3(S_ / 256, S_ / 256, B_), dim3(512), 0, stream>>>(qh, ql, kh, kl, attn);
    k_pv<<<dim3(D_ / 256, S_ / 256, B_), dim3(512), 0, stream>>>(attn, vt, out);
}

// Round 7
// 344.927 us; speedup vs baseline: 8.3419x; 8.3419x over previous
//
#include <hip/hip_runtime.h>
#include <stdint.h>

typedef unsigned short u16;
typedef short bf16x8 __attribute__((ext_vector_type(8)));
typedef float f32x4 __attribute__((ext_vector_type(4)));

#define B_   4
#define S_   2048
#define D_   1024
#define ND3  3072

// RNE float->bf16
__device__ __forceinline__ u16 f2bf(float x) {
    union { float f; uint32_t u; } v; v.f = x;
    uint32_t r = v.u + 0x7fffu + ((v.u >> 16) & 1u);
    return (u16)(r >> 16);
}
__device__ __forceinline__ float bf2f(u16 h) {
    union { uint32_t u; float f; } v; v.u = ((uint32_t)h) << 16;
    return v.f;
}

__device__ __forceinline__ void gload_lds16(const u16* g, u16* l) {
    __builtin_amdgcn_global_load_lds((const __attribute__((address_space(1))) void*)g,
                                     (__attribute__((address_space(3))) void*)l, 16, 0, 0);
}

// bijective XCD swizzle for nwg % 8 == 0
__device__ __forceinline__ int xcd_swz(int lid, int nwg) {
    int c = nwg >> 3;
    return (lid & 7) * c + (lid >> 3);
}

// ================= 256x256 bf16 GEMM core, K-step=32 double-buffer =================
// acc += sum_s A_s @ B_s^T over NSEG segments, each K = NTSEG*64 (steps of 32).
// 512 threads = 8 waves (2Mrow x 4Ncol), per-wave output 128x64.
// LDS 64KB: A [2 slots][256r][32k] + B [2 slots][256r][32k]; slot = step & 1.
// Swizzle: logical chunk c (16B) of row r stored at c ^ ((r>>1)&3); applied on
// the global SOURCE address (linear LDS dest) and identically on ds_read.
// Race-free schedule per step S:
//   lgkmcnt(0)            -- own reads of slot (S-1)&1 drained
//   barrier               -- ALL waves drained slot (S+1)&1's previous readers
//   ISSUE(S+1)            -- 4 loads into slot (S+1)&1 (safe: just drained)
//   vmcnt(4)              -- own step-S loads landed (S+1's 4 still in flight)
//   barrier               -- all waves' step-S loads landed
//   body: 12 ds_read_b128 + 32 MFMA, no fences (compiler inserts lgkmcnt)
// Writes to a slot always follow a barrier that followed the lgkm-drain of all
// of that slot's readers => no read/write race. Prefetch distance = 1 body.
template<int NSEG, int NTSEG>
__device__ __forceinline__ void gemm256(const u16* __restrict__ a0, const u16* __restrict__ b0,
                                        const u16* __restrict__ a1, const u16* __restrict__ b1,
                                        const u16* __restrict__ a2, const u16* __restrict__ b2,
                                        int lda, int ldb, int rowbase, int colbase,
                                        u16* ldsA, u16* ldsB, f32x4 (&acc)[8][4])
{
    const int NSTEP = 2 * NSEG * NTSEG;
    const int tid  = threadIdx.x;
    const int lane = tid & 63;
    const int w    = tid >> 6;
    const int wr   = w >> 2, wc = w & 3;

    // staging: thread tid -> row r0 = tid>>2 (and r0+128), physical chunk tid&3
    // (linear dest), global source chunk = (tid&3) ^ ((r0>>1)&3)
    const int r0 = tid >> 2;
    const int c0 = (((tid & 3) ^ ((tid >> 3) & 3)) << 3);
    const size_t offA0 = (size_t)(rowbase + r0) * lda + c0;
    const size_t offA1 = offA0 + (size_t)128 * lda;
    const size_t offB0 = (size_t)(colbase + r0) * ldb + c0;
    const size_t offB1 = offB0 + (size_t)128 * ldb;
    const int dst0 = tid << 3;            // u16 units within 8192-u16 slot
    const int dst1 = 4096 + (tid << 3);

    // ds_read per-lane: row = fragbase + (lane&15), logical chunk = lane>>4,
    // physical chunk = (lane>>4) ^ ((row>>1)&3)
    const int rd_lane = ((lane & 15) << 5) + ((((lane >> 4) ^ (lane >> 1)) & 3) << 3);
    const int wrOff = wr << 12;           // wr*128 rows * 32 u16
    const int wcOff = wc << 11;           // wc*64 rows * 32 u16

#define ISSUE(sv) do { int s_ = (sv); \
    if (s_ < NSTEP) { \
        int local_ = s_ & (2 * NTSEG - 1); \
        const u16* Ab_; const u16* Bb_; \
        if (NSEG == 1) { Ab_ = a0; Bb_ = b0; } \
        else { int seg_ = s_ / (2 * NTSEG); \
               Ab_ = seg_ == 0 ? a0 : (seg_ == 1 ? a1 : a2); \
               Bb_ = seg_ == 0 ? b0 : (seg_ == 1 ? b1 : b2); } \
        size_t ko_ = (size_t)local_ << 5; \
        int sl_ = (s_ & 1) << 13; \
        gload_lds16(Ab_ + offA0 + ko_, ldsA + sl_ + dst0); \
        gload_lds16(Ab_ + offA1 + ko_, ldsA + sl_ + dst1); \
        gload_lds16(Bb_ + offB0 + ko_, ldsB + sl_ + dst0); \
        gload_lds16(Bb_ + offB1 + ko_, ldsB + sl_ + dst1); \
    } } while (0)

    bf16x8 af[4], bf[4];

#define LDA4(sl, mh) { _Pragma("unroll") for (int mq = 0; mq < 4; ++mq) \
    af[mq] = *(const bf16x8*)(ldsA + (sl) + wrOff + ((mh) << 11) + (mq << 9) + rd_lane); }
#define LDB4(sl) { _Pragma("unroll") for (int n = 0; n < 4; ++n) \
    bf[n] = *(const bf16x8*)(ldsB + (sl) + wcOff + (n << 9) + rd_lane); }
#define MFMA16(mh) { __builtin_amdgcn_s_setprio(1); \
    _Pragma("unroll") for (int mq = 0; mq < 4; ++mq) \
    _Pragma("unroll") for (int n = 0; n < 4; ++n) \
        acc[(mh) * 4 + mq][n] = __builtin_amdgcn_mfma_f32_16x16x32_bf16(af[mq], bf[n], acc[(mh) * 4 + mq][n], 0, 0, 0); \
    __builtin_amdgcn_s_setprio(0); }

#define STEP(sv, sl) { \
    asm volatile("s_waitcnt lgkmcnt(0)" ::: "memory"); \
    __builtin_amdgcn_s_barrier(); \
    asm volatile("" ::: "memory"); \
    ISSUE((sv) + 1); \
    if ((sv) < NSTEP - 1) asm volatile("s_waitcnt vmcnt(4)" ::: "memory"); \
    else                  asm volatile("s_waitcnt vmcnt(0)" ::: "memory"); \
    __builtin_amdgcn_s_barrier(); \
    asm volatile("" ::: "memory"); \
    LDA4(sl, 0); LDB4(sl); \
    MFMA16(0); \
    LDA4(sl, 1); \
    MFMA16(1); }

    ISSUE(0);
    for (int T = 0; T < NSEG * NTSEG; ++T) {
        STEP(2 * T,     0)
        STEP(2 * T + 1, 8192)
    }
#undef STEP
#undef MFMA16
#undef LDB4
#undef LDA4
#undef ISSUE
}

// ---------------- stage 0a: fp32 -> (hi, lo) bf16 split ----------------
__global__ __launch_bounds__(256) void k_split_f32(const float* __restrict__ in,
                                                   u16* __restrict__ oh,
                                                   u16* __restrict__ ol, int n) {
    int i = (blockIdx.x * 256 + threadIdx.x) << 3;
    if (i >= n) return;
    float4 a = *(const float4*)(in + i);
    float4 b = *(const float4*)(in + i + 4);
    ushort4 h0, h1, l0, l1;
    h0.x = f2bf(a.x); l0.x = f2bf(a.x - bf2f(h0.x));
    h0.y = f2bf(a.y); l0.y = f2bf(a.y - bf2f(h0.y));
    h0.z = f2bf(a.z); l0.z = f2bf(a.z - bf2f(h0.z));
    h0.w = f2bf(a.w); l0.w = f2bf(a.w - bf2f(h0.w));
    h1.x = f2bf(b.x); l1.x = f2bf(b.x - bf2f(h1.x));
    h1.y = f2bf(b.y); l1.y = f2bf(b.y - bf2f(h1.y));
    h1.z = f2bf(b.z); l1.z = f2bf(b.z - bf2f(h1.z));
    h1.w = f2bf(b.w); l1.w = f2bf(b.w - bf2f(h1.w));
    *(ushort4*)(oh + i)     = h0;
    *(ushort4*)(oh + i + 4) = h1;
    *(ushort4*)(ol + i)     = l0;
    *(ushort4*)(ol + i + 4) = l1;
}

// ---------------- stage 0b: W [R][C] fp32 -> Wt hi/lo [C][R] bf16 ----------------
__global__ __launch_bounds__(256) void k_transpose_split(const float* __restrict__ W,
                                                         u16* __restrict__ Wth,
                                                         u16* __restrict__ Wtl, int R, int C) {
    __shared__ float t[32][33];
    int tx = threadIdx.x & 31, ty = threadIdx.x >> 5;
    int c0 = blockIdx.x << 5, r0 = blockIdx.y << 5;
#pragma unroll
    for (int i = 0; i < 4; ++i) {
        int r = (i << 3) + ty;
        t[r][tx] = W[(size_t)(r0 + r) * C + c0 + tx];
    }
    __syncthreads();
#pragma unroll
    for (int i = 0; i < 4; ++i) {
        int r = (i << 3) + ty;
        float w = t[tx][r];
        u16 h = f2bf(w);
        Wth[(size_t)(c0 + r) * R + r0 + tx] = h;
        Wtl[(size_t)(c0 + r) * R + r0 + tx] = f2bf(w - bf2f(h));
    }
}

// ---------------- stage 1: QKV (hi/lo 3-seg fused); split-store q,k; v transposed ----------------
__global__ __launch_bounds__(512, 2) void k_qkv(const u16* __restrict__ xh,
                                                const u16* __restrict__ xl,
                                                const u16* __restrict__ wth,
                                                const u16* __restrict__ wtl,
                                                const float* __restrict__ bias,
                                                u16* __restrict__ qhi, u16* __restrict__ qlo,
                                                u16* __restrict__ khi, u16* __restrict__ klo,
                                                u16* __restrict__ vt) {
    __shared__ u16 lds[32768];
    f32x4 acc[8][4];
    f32x4 z = {0.f, 0.f, 0.f, 0.f};
#pragma unroll
    for (int m = 0; m < 8; ++m)
#pragma unroll
        for (int n = 0; n < 4; ++n) acc[m][n] = z;

    // T1 bijective XCD swizzle over 12x32 = 384 wgs
    const int lid = blockIdx.y * 12 + blockIdx.x;
    const int swz = xcd_swz(lid, 384);
    const int bx = swz % 12, by = swz / 12;
    const int rowbase = by << 8;
    const int colbase = bx << 8;
    gemm256<3, 16>(xh, wth, xh, wtl, xl, wth, D_, D_, rowbase, colbase,
                   lds, lds + 16384, acc);

    const int lane = threadIdx.x & 63;
    const int w = threadIdx.x >> 6;
    const int wr = w >> 2, wc = w & 3;
    const int region = colbase >> 10;   // 0=q, 1=k, 2=v (256 | 1024)
#pragma unroll
    for (int m = 0; m < 8; ++m) {
        int gr0 = rowbase + wr * 128 + m * 16 + ((lane >> 4) << 2);
#pragma unroll
        for (int n = 0; n < 4; ++n) {
            int gc = colbase + wc * 64 + n * 16 + (lane & 15);
            float bv = bias[gc];
            if (region == 0) {
#pragma unroll
                for (int r = 0; r < 4; ++r) {
                    float val = acc[m][n][r] + bv;
                    u16 h = f2bf(val);
                    size_t idx = (size_t)(gr0 + r) * D_ + gc;
                    qhi[idx] = h;
                    qlo[idx] = f2bf(val - bf2f(h));
                }
            } else if (region == 1) {
                int c = gc - 1024;
#pragma unroll
                for (int r = 0; r < 4; ++r) {
                    float val = acc[m][n][r] + bv;
                    u16 h = f2bf(val);
                    size_t idx = (size_t)(gr0 + r) * D_ + c;
                    khi[idx] = h;
                    klo[idx] = f2bf(val - bf2f(h));
                }
            } else {
                int d  = gc - 2048;
                int b  = gr0 >> 11;
                int t0 = gr0 & 2047;
                size_t base = (((size_t)b << 10) + d) * (size_t)S_ + t0;
#pragma unroll
                for (int r = 0; r < 4; ++r)
                    vt[base + r] = f2bf(acc[m][n][r] + bv);
            }
        }
    }
}

// ---------------- stage 2: attn = sigmoid(32 * q @ k^T) (3-seg fused), bf16 ----------------
__global__ __launch_bounds__(512, 2) void k_scores(const u16* __restrict__ qhi,
                                                   const u16* __restrict__ qlo,
                                                   const u16* __restrict__ khi,
                                                   const u16* __restrict__ klo,
                                                   u16* __restrict__ attn) {
    __shared__ u16 lds[32768];
    f32x4 acc[8][4];
    f32x4 z = {0.f, 0.f, 0.f, 0.f};
#pragma unroll
    for (int m = 0; m < 8; ++m)
#pragma unroll
        for (int n = 0; n < 4; ++n) acc[m][n] = z;

    // swizzle over 8x8x4 = 256 wgs
    const int lid = (blockIdx.z << 6) + (blockIdx.y << 3) + blockIdx.x;
    const int swz = xcd_swz(lid, 256);
    const int bx = swz & 7, by = (swz >> 3) & 7, b = swz >> 6;

    const size_t boff = (size_t)b * S_ * D_;
    u16* att = attn + (size_t)b * S_ * S_;
    const int rowbase = by << 8, colbase = bx << 8;
    gemm256<3, 16>(qhi + boff, khi + boff, qhi + boff, klo + boff, qlo + boff, khi + boff,
                   D_, D_, rowbase, colbase, lds, lds + 16384, acc);

    const int lane = threadIdx.x & 63;
    const int w = threadIdx.x >> 6;
    const int wr = w >> 2, wc = w & 3;
#pragma unroll
    for (int m = 0; m < 8; ++m) {
        int gr0 = rowbase + wr * 128 + m * 16 + ((lane >> 4) << 2);
#pragma unroll
        for (int n = 0; n < 4; ++n) {
            int gc = colbase + wc * 64 + n * 16 + (lane & 15);
#pragma unroll
            for (int r = 0; r < 4; ++r) {
                float sv = acc[m][n][r] * 32.0f;
                float sg = 1.0f / (1.0f + __expf(-sv));
                att[(size_t)(gr0 + r) * S_ + gc] = f2bf(sg);
            }
        }
    }
}

// ---------------- stage 3: out = attn @ v  (Bt = v^T [D][S]) ----------------
__global__ __launch_bounds__(512, 2) void k_pv(const u16* __restrict__ attn,
                                               const u16* __restrict__ vt,
                                               float* __restrict__ out) {
    __shared__ u16 lds[32768];
    f32x4 acc[8][4];
    f32x4 z = {0.f, 0.f, 0.f, 0.f};
#pragma unroll
    for (int m = 0; m < 8; ++m)
#pragma unroll
        for (int n = 0; n < 4; ++n) acc[m][n] = z;

    // swizzle over 4x8x4 = 128 wgs
    const int lid = (blockIdx.z << 5) + (blockIdx.y << 2) + blockIdx.x;
    const int swz = xcd_swz(lid, 128);
    const int bx = swz & 3, by = (swz >> 2) & 7, b = swz >> 5;

    const u16* Aa = attn + (size_t)b * S_ * S_;
    const u16* Bv = vt   + (size_t)b * D_ * S_;
    float* ob     = out  + (size_t)b * S_ * D_;
    const int rowbase = by << 8, colbase = bx << 8;
    gemm256<1, 32>(Aa, Bv, Aa, Bv, Aa, Bv, S_, S_, rowbase, colbase,
                   lds, lds + 16384, acc);

    const int lane = threadIdx.x & 63;
    const int w = threadIdx.x >> 6;
    const int wr = w >> 2, wc = w & 3;
#pragma unroll
    for (int m = 0; m < 8; ++m) {
        int gr0 = rowbase + wr * 128 + m * 16 + ((lane >> 4) << 2);
#pragma unroll
        for (int n = 0; n < 4; ++n) {
            int gc = colbase + wc * 64 + n * 16 + (lane & 15);
#pragma unroll
            for (int r = 0; r < 4; ++r)
                ob[(size_t)(gr0 + r) * D_ + gc] = acc[m][n][r];
        }
    }
}

extern "C" void kernel_launch(void* const* d_in, const int* in_sizes, int n_in,
                              void* d_out, int out_size, void* d_ws, size_t ws_size,
                              hipStream_t stream) {
    const float* x    = (const float*)d_in[0];
    const float* wqkv = (const float*)d_in[1];
    const float* bias = (const float*)d_in[2];
    float* out = (float*)d_out;

    const size_t MB = 1048576;
    uint8_t* ws = (uint8_t*)d_ws;
    u16* xh   = (u16*)(ws);              // [8192][1024] bf16   16 MB
    u16* xl   = (u16*)(ws + 16 * MB);    // 16 MB
    u16* wth  = (u16*)(ws + 32 * MB);    // [3072][1024] bf16    6 MB
    u16* wtl  = (u16*)(ws + 38 * MB);    //  6 MB
    u16* qh   = (u16*)(ws + 44 * MB);    // [B][S][D] bf16      16 MB
    u16* ql   = (u16*)(ws + 60 * MB);    // 16 MB
    u16* kh   = (u16*)(ws + 76 * MB);    // 16 MB
    u16* kl   = (u16*)(ws + 92 * MB);    // 16 MB
    u16* vt   = (u16*)(ws + 108 * MB);   // [B][D][S] bf16      16 MB (ends 124 MB)
    u16* attn = (u16*)(ws);              // [B][S][S] bf16 32 MB — aliases xh/xl (dead after QKV)

    k_split_f32<<<dim3(4096), dim3(256), 0, stream>>>(x, xh, xl, B_ * S_ * D_);
    k_transpose_split<<<dim3(ND3 / 32, D_ / 32), dim3(256), 0, stream>>>(wqkv, wth, wtl, D_, ND3);
    k_qkv<<<dim3(ND3 / 256, (B_ * S_) / 256), dim3(512), 0, stream>>>(xh, xl, wth, wtl, bias,
                                                                      qh, ql, kh, kl, vt);
    k_scores<<<dim3(S_ / 256, S_ / 256, B_), dim3(512), 0, stream>>>(qh, ql, kh, kl, attn);
    k_pv<<<dim3(D_ / 256, S_ / 256, B_), dim3(512), 0, stream>>>(attn, vt, out);
}

// Round 8
// 323.693 us; speedup vs baseline: 8.8891x; 1.0656x over previous
//
#include <hip/hip_runtime.h>
#include <stdint.h>

typedef unsigned short u16;
typedef short bf16x8 __attribute__((ext_vector_type(8)));
typedef float f32x4 __attribute__((ext_vector_type(4)));

#define B_   4
#define S_   2048
#define D_   1024
#define ND3  3072

// RNE float->bf16
__device__ __forceinline__ u16 f2bf(float x) {
    union { float f; uint32_t u; } v; v.f = x;
    uint32_t r = v.u + 0x7fffu + ((v.u >> 16) & 1u);
    return (u16)(r >> 16);
}
__device__ __forceinline__ float bf2f(u16 h) {
    union { uint32_t u; float f; } v; v.u = ((uint32_t)h) << 16;
    return v.f;
}

__device__ __forceinline__ void gload_lds16(const u16* g, u16* l) {
    __builtin_amdgcn_global_load_lds((const __attribute__((address_space(1))) void*)g,
                                     (__attribute__((address_space(3))) void*)l, 16, 0, 0);
}

// bijective XCD swizzle for nwg % 8 == 0
__device__ __forceinline__ int xcd_swz(int lid, int nwg) {
    int c = nwg >> 3;
    return (lid & 7) * c + (lid >> 3);
}

// ============ 128x256 bf16 GEMM core, K-step=32 double-buffer, 2 blocks/CU ============
// acc += sum_s A_s @ B_s^T over NSEG segments, each K = NTSEG*64 (steps of 32).
// 512 threads = 8 waves (2Mrow x 4Ncol), per-wave output 64x64, acc[4][4] (64 VGPR).
// LDS 48KB: A [2 slots][128r][32k] (16KB) + B [2 slots][256r][32k] (32KB); slot = step&1.
// Swizzle: logical chunk c (16B) of row r stored at c ^ ((r>>1)&3); applied on the
// global SOURCE address (linear LDS dest) and identically on ds_read (both sides).
// Race-free schedule per step S (proven r7):
//   lgkmcnt(0); barrier; ISSUE(S+1); vmcnt(3) [own step-S loads landed]; barrier;
//   body: 8 ds_read_b128 + 16 MFMA, no fences (compiler inserts fine-grained lgkm).
// 2 blocks/CU (goal of this revision) hides barrier skew via cross-block overlap (m114).
template<int NSEG, int NTSEG>
__device__ __forceinline__ void gemm128(const u16* __restrict__ a0, const u16* __restrict__ b0,
                                        const u16* __restrict__ a1, const u16* __restrict__ b1,
                                        const u16* __restrict__ a2, const u16* __restrict__ b2,
                                        int lda, int ldb, int rowbase, int colbase,
                                        u16* ldsA, u16* ldsB, f32x4 (&acc)[4][4])
{
    const int NSTEP = 2 * NSEG * NTSEG;
    const int tid  = threadIdx.x;
    const int lane = tid & 63;
    const int w    = tid >> 6;
    const int wr   = w >> 2, wc = w & 3;

    // staging: thread tid -> row r0 = tid>>2 (A; B also r0+128), phys chunk tid&3
    // (linear dest), global source chunk = (tid&3) ^ ((r0>>1)&3)
    const int r0 = tid >> 2;
    const int c0 = (((tid & 3) ^ ((tid >> 3) & 3)) << 3);
    const uint32_t offA0 = (uint32_t)(rowbase + r0) * lda + c0;
    const uint32_t offB0 = (uint32_t)(colbase + r0) * ldb + c0;
    const uint32_t offB1 = offB0 + (uint32_t)128 * ldb;
    const int dst = tid << 3;

    // ds_read per-lane: row = fragbase + (lane&15), logical chunk = lane>>4,
    // physical chunk = (lane>>4) ^ ((row>>1)&3)
    const int rd_lane = ((lane & 15) << 5) + ((((lane >> 4) ^ (lane >> 1)) & 3) << 3);
    const int wrOff = wr << 11;           // wr*64 rows * 32 u16
    const int wcOff = wc << 11;           // wc*64 rows * 32 u16

#define ISSUE(sv) do { int s_ = (sv); \
    if (s_ < NSTEP) { \
        const u16 *Ab_, *Bb_; \
        if (NSEG == 1) { Ab_ = a0; Bb_ = b0; } \
        else { int seg_ = s_ / (2 * NTSEG); \
               Ab_ = seg_ == 0 ? a0 : (seg_ == 1 ? a1 : a2); \
               Bb_ = seg_ == 0 ? b0 : (seg_ == 1 ? b1 : b2); } \
        int local_ = s_ & (2 * NTSEG - 1); \
        uint32_t ko_ = (uint32_t)local_ << 5; \
        int slA_ = (s_ & 1) << 12, slB_ = (s_ & 1) << 13; \
        gload_lds16(Ab_ + offA0 + ko_, ldsA + slA_ + dst); \
        gload_lds16(Bb_ + offB0 + ko_, ldsB + slB_ + dst); \
        gload_lds16(Bb_ + offB1 + ko_, ldsB + slB_ + dst + 4096); \
    } } while (0)

    bf16x8 af[4], bf[4];

#define STEP(sv, slA, slB) { \
    asm volatile("s_waitcnt lgkmcnt(0)" ::: "memory"); \
    __builtin_amdgcn_s_barrier(); \
    asm volatile("" ::: "memory"); \
    ISSUE((sv) + 1); \
    if ((sv) < NSTEP - 1) asm volatile("s_waitcnt vmcnt(3)" ::: "memory"); \
    else                  asm volatile("s_waitcnt vmcnt(0)" ::: "memory"); \
    __builtin_amdgcn_s_barrier(); \
    asm volatile("" ::: "memory"); \
    _Pragma("unroll") for (int mq = 0; mq < 4; ++mq) \
        af[mq] = *(const bf16x8*)(ldsA + (slA) + wrOff + (mq << 9) + rd_lane); \
    _Pragma("unroll") for (int n = 0; n < 4; ++n) \
        bf[n] = *(const bf16x8*)(ldsB + (slB) + wcOff + (n << 9) + rd_lane); \
    _Pragma("unroll") for (int mq = 0; mq < 4; ++mq) \
    _Pragma("unroll") for (int n = 0; n < 4; ++n) \
        acc[mq][n] = __builtin_amdgcn_mfma_f32_16x16x32_bf16(af[mq], bf[n], acc[mq][n], 0, 0, 0); }

    ISSUE(0);
    for (int T = 0; T < NSEG * NTSEG; ++T) {
        STEP(2 * T,     0,    0)
        STEP(2 * T + 1, 4096, 8192)
    }
#undef STEP
#undef ISSUE
}

// ---------------- stage 0a: fp32 -> (hi, lo) bf16 split ----------------
__global__ __launch_bounds__(256) void k_split_f32(const float* __restrict__ in,
                                                   u16* __restrict__ oh,
                                                   u16* __restrict__ ol, int n) {
    int i = (blockIdx.x * 256 + threadIdx.x) << 3;
    if (i >= n) return;
    float4 a = *(const float4*)(in + i);
    float4 b = *(const float4*)(in + i + 4);
    ushort4 h0, h1, l0, l1;
    h0.x = f2bf(a.x); l0.x = f2bf(a.x - bf2f(h0.x));
    h0.y = f2bf(a.y); l0.y = f2bf(a.y - bf2f(h0.y));
    h0.z = f2bf(a.z); l0.z = f2bf(a.z - bf2f(h0.z));
    h0.w = f2bf(a.w); l0.w = f2bf(a.w - bf2f(h0.w));
    h1.x = f2bf(b.x); l1.x = f2bf(b.x - bf2f(h1.x));
    h1.y = f2bf(b.y); l1.y = f2bf(b.y - bf2f(h1.y));
    h1.z = f2bf(b.z); l1.z = f2bf(b.z - bf2f(h1.z));
    h1.w = f2bf(b.w); l1.w = f2bf(b.w - bf2f(h1.w));
    *(ushort4*)(oh + i)     = h0;
    *(ushort4*)(oh + i + 4) = h1;
    *(ushort4*)(ol + i)     = l0;
    *(ushort4*)(ol + i + 4) = l1;
}

// ---------------- stage 0b: W [R][C] fp32 -> Wt hi/lo [C][R] bf16 ----------------
__global__ __launch_bounds__(256) void k_transpose_split(const float* __restrict__ W,
                                                         u16* __restrict__ Wth,
                                                         u16* __restrict__ Wtl, int R, int C) {
    __shared__ float t[32][33];
    int tx = threadIdx.x & 31, ty = threadIdx.x >> 5;
    int c0 = blockIdx.x << 5, r0 = blockIdx.y << 5;
#pragma unroll
    for (int i = 0; i < 4; ++i) {
        int r = (i << 3) + ty;
        t[r][tx] = W[(size_t)(r0 + r) * C + c0 + tx];
    }
    __syncthreads();
#pragma unroll
    for (int i = 0; i < 4; ++i) {
        int r = (i << 3) + ty;
        float w = t[tx][r];
        u16 h = f2bf(w);
        Wth[(size_t)(c0 + r) * R + r0 + tx] = h;
        Wtl[(size_t)(c0 + r) * R + r0 + tx] = f2bf(w - bf2f(h));
    }
}

// ---------------- stage 1: QKV (hi/lo 3-seg fused); split-store q,k; v transposed ----------------
__global__ __launch_bounds__(512, 4) void k_qkv(const u16* __restrict__ xh,
                                                const u16* __restrict__ xl,
                                                const u16* __restrict__ wth,
                                                const u16* __restrict__ wtl,
                                                const float* __restrict__ bias,
                                                u16* __restrict__ qhi, u16* __restrict__ qlo,
                                                u16* __restrict__ khi, u16* __restrict__ klo,
                                                u16* __restrict__ vt) {
    __shared__ u16 lds[24576];            // A 8192 u16 + B 16384 u16 = 48 KB
    f32x4 acc[4][4];
    f32x4 z = {0.f, 0.f, 0.f, 0.f};
#pragma unroll
    for (int m = 0; m < 4; ++m)
#pragma unroll
        for (int n = 0; n < 4; ++n) acc[m][n] = z;

    // T1 bijective XCD swizzle over 12x64 = 768 wgs
    const int lid = blockIdx.y * 12 + blockIdx.x;
    const int swz = xcd_swz(lid, 768);
    const int bx = swz % 12, by = swz / 12;
    const int rowbase = by << 7;          // BM = 128
    const int colbase = bx << 8;          // BN = 256
    gemm128<3, 16>(xh, wth, xh, wtl, xl, wth, D_, D_, rowbase, colbase,
                   lds, lds + 8192, acc);

    const int lane = threadIdx.x & 63;
    const int w = threadIdx.x >> 6;
    const int wr = w >> 2, wc = w & 3;
    const int region = colbase >> 10;     // 0=q, 1=k, 2=v (256 | 1024)
#pragma unroll
    for (int m = 0; m < 4; ++m) {
        int gr0 = rowbase + wr * 64 + m * 16 + ((lane >> 4) << 2);
#pragma unroll
        for (int n = 0; n < 4; ++n) {
            int gc = colbase + wc * 64 + n * 16 + (lane & 15);
            float bv = bias[gc];
            if (region == 0) {
#pragma unroll
                for (int r = 0; r < 4; ++r) {
                    float val = acc[m][n][r] + bv;
                    u16 h = f2bf(val);
                    size_t idx = (size_t)(gr0 + r) * D_ + gc;
                    qhi[idx] = h;
                    qlo[idx] = f2bf(val - bf2f(h));
                }
            } else if (region == 1) {
                int c = gc - 1024;
#pragma unroll
                for (int r = 0; r < 4; ++r) {
                    float val = acc[m][n][r] + bv;
                    u16 h = f2bf(val);
                    size_t idx = (size_t)(gr0 + r) * D_ + c;
                    khi[idx] = h;
                    klo[idx] = f2bf(val - bf2f(h));
                }
            } else {
                int d  = gc - 2048;
                int b  = gr0 >> 11;
                int t0 = gr0 & 2047;
                size_t base = (((size_t)b << 10) + d) * (size_t)S_ + t0;
#pragma unroll
                for (int r = 0; r < 4; ++r)
                    vt[base + r] = f2bf(acc[m][n][r] + bv);
            }
        }
    }
}

// ---------------- stage 2: attn = sigmoid(32 * q @ k^T) (3-seg fused), bf16 ----------------
__global__ __launch_bounds__(512, 4) void k_scores(const u16* __restrict__ qhi,
                                                   const u16* __restrict__ qlo,
                                                   const u16* __restrict__ khi,
                                                   const u16* __restrict__ klo,
                                                   u16* __restrict__ attn) {
    __shared__ u16 lds[24576];
    f32x4 acc[4][4];
    f32x4 z = {0.f, 0.f, 0.f, 0.f};
#pragma unroll
    for (int m = 0; m < 4; ++m)
#pragma unroll
        for (int n = 0; n < 4; ++n) acc[m][n] = z;

    // swizzle over 8x16x4 = 512 wgs
    const int lid = (blockIdx.z << 7) + (blockIdx.y << 3) + blockIdx.x;
    const int swz = xcd_swz(lid, 512);
    const int bx = swz & 7, by = (swz >> 3) & 15, b = swz >> 7;

    const size_t boff = (size_t)b * S_ * D_;
    u16* att = attn + (size_t)b * S_ * S_;
    const int rowbase = by << 7, colbase = bx << 8;
    gemm128<3, 16>(qhi + boff, khi + boff, qhi + boff, klo + boff, qlo + boff, khi + boff,
                   D_, D_, rowbase, colbase, lds, lds + 8192, acc);

    const int lane = threadIdx.x & 63;
    const int w = threadIdx.x >> 6;
    const int wr = w >> 2, wc = w & 3;
#pragma unroll
    for (int m = 0; m < 4; ++m) {
        int gr0 = rowbase + wr * 64 + m * 16 + ((lane >> 4) << 2);
#pragma unroll
        for (int n = 0; n < 4; ++n) {
            int gc = colbase + wc * 64 + n * 16 + (lane & 15);
#pragma unroll
            for (int r = 0; r < 4; ++r) {
                float sv = acc[m][n][r] * 32.0f;
                float sg = 1.0f / (1.0f + __expf(-sv));
                att[(size_t)(gr0 + r) * S_ + gc] = f2bf(sg);
            }
        }
    }
}

// ---------------- stage 3: out = attn @ v  (Bt = v^T [D][S]) ----------------
__global__ __launch_bounds__(512, 4) void k_pv(const u16* __restrict__ attn,
                                               const u16* __restrict__ vt,
                                               float* __restrict__ out) {
    __shared__ u16 lds[24576];
    f32x4 acc[4][4];
    f32x4 z = {0.f, 0.f, 0.f, 0.f};
#pragma unroll
    for (int m = 0; m < 4; ++m)
#pragma unroll
        for (int n = 0; n < 4; ++n) acc[m][n] = z;

    // swizzle over 4x16x4 = 256 wgs
    const int lid = (blockIdx.z << 6) + (blockIdx.y << 2) + blockIdx.x;
    const int swz = xcd_swz(lid, 256);
    const int bx = swz & 3, by = (swz >> 2) & 15, b = swz >> 6;

    const u16* Aa = attn + (size_t)b * S_ * S_;
    const u16* Bv = vt   + (size_t)b * D_ * S_;
    float* ob     = out  + (size_t)b * S_ * D_;
    const int rowbase = by << 7, colbase = bx << 8;
    gemm128<1, 32>(Aa, Bv, Aa, Bv, Aa, Bv, S_, S_, rowbase, colbase,
                   lds, lds + 8192, acc);

    const int lane = threadIdx.x & 63;
    const int w = threadIdx.x >> 6;
    const int wr = w >> 2, wc = w & 3;
#pragma unroll
    for (int m = 0; m < 4; ++m) {
        int gr0 = rowbase + wr * 64 + m * 16 + ((lane >> 4) << 2);
#pragma unroll
        for (int n = 0; n < 4; ++n) {
            int gc = colbase + wc * 64 + n * 16 + (lane & 15);
#pragma unroll
            for (int r = 0; r < 4; ++r)
                ob[(size_t)(gr0 + r) * D_ + gc] = acc[m][n][r];
        }
    }
}

extern "C" void kernel_launch(void* const* d_in, const int* in_sizes, int n_in,
                              void* d_out, int out_size, void* d_ws, size_t ws_size,
                              hipStream_t stream) {
    const float* x    = (const float*)d_in[0];
    const float* wqkv = (const float*)d_in[1];
    const float* bias = (const float*)d_in[2];
    float* out = (float*)d_out;

    const size_t MB = 1048576;
    uint8_t* ws = (uint8_t*)d_ws;
    u16* xh   = (u16*)(ws);              // [8192][1024] bf16   16 MB
    u16* xl   = (u16*)(ws + 16 * MB);    // 16 MB
    u16* wth  = (u16*)(ws + 32 * MB);    // [3072][1024] bf16    6 MB
    u16* wtl  = (u16*)(ws + 38 * MB);    //  6 MB
    u16* qh   = (u16*)(ws + 44 * MB);    // [B][S][D] bf16      16 MB
    u16* ql   = (u16*)(ws + 60 * MB);    // 16 MB
    u16* kh   = (u16*)(ws + 76 * MB);    // 16 MB
    u16* kl   = (u16*)(ws + 92 * MB);    // 16 MB
    u16* vt   = (u16*)(ws + 108 * MB);   // [B][D][S] bf16      16 MB (ends 124 MB)
    u16* attn = (u16*)(ws);              // [B][S][S] bf16 32 MB — aliases xh/xl (dead after QKV)

    k_split_f32<<<dim3(4096), dim3(256), 0, stream>>>(x, xh, xl, B_ * S_ * D_);
    k_transpose_split<<<dim3(ND3 / 32, D_ / 32), dim3(256), 0, stream>>>(wqkv, wth, wtl, D_, ND3);
    k_qkv<<<dim3(ND3 / 256, (B_ * S_) / 128), dim3(512), 0, stream>>>(xh, xl, wth, wtl, bias,
                                                                      qh, ql, kh, kl, vt);
    k_scores<<<dim3(S_ / 256, S_ / 128, B_), dim3(512), 0, stream>>>(qh, ql, kh, kl, attn);
    k_pv<<<dim3(D_ / 256, S_ / 128, B_), dim3(512), 0, stream>>>(attn, vt, out);
}

// Round 10
// 161.532 us; speedup vs baseline: 17.8128x; 2.0039x over previous
//
#include <hip/hip_runtime.h>
#include <stdint.h>

typedef unsigned short u16;
typedef _Float16 f16x8 __attribute__((ext_vector_type(8)));
typedef float f32x4 __attribute__((ext_vector_type(4)));

#define B_   4
#define S_   2048
#define D_   1024
#define ND3  3072

__device__ __forceinline__ u16 f2h(float x) {
    union { _Float16 h; u16 u; } v; v.h = (_Float16)x; return v.u;
}

__device__ __forceinline__ void gload_lds16(const u16* g, u16* l) {
    __builtin_amdgcn_global_load_lds((const __attribute__((address_space(1))) void*)g,
                                     (__attribute__((address_space(3))) void*)l, 16, 0, 0);
}

// bijective XCD swizzle for nwg % 8 == 0
__device__ __forceinline__ int xcd_swz(int lid, int nwg) {
    int c = nwg >> 3;
    return (lid & 7) * c + (lid >> 3);
}

// ============ 128x256 fp16 GEMM core, K-step=32 double-buffer, 2 blocks/CU ============
// acc += A @ B^T, K = NT*64 (steps of 32). 512 threads = 8 waves (2Mrow x 4Ncol),
// per-wave output 64x64, acc[4][4]. LDS 48KB: A [2][128r][32k] + B [2][256r][32k].
// Swizzle: chunk c of row r stored at c ^ ((r>>1)&3), applied on global SOURCE
// (linear LDS dest) and identically on ds_read. Race-free step (proven r7/r8):
//   lgkmcnt(0); barrier; ISSUE(S+1); vmcnt(3); barrier; body (8 ds_read + 16 MFMA).
template<int NT>
__device__ __forceinline__ void gemm_wide(const u16* __restrict__ A, const u16* __restrict__ Bt,
                                          int lda, int ldb, int rowbase, int colbase,
                                          u16* ldsA, u16* ldsB, f32x4 (&acc)[4][4])
{
    const int NSTEP = 2 * NT;
    const int tid  = threadIdx.x;
    const int lane = tid & 63;
    const int w    = tid >> 6;
    const int wr   = w >> 2, wc = w & 3;

    const int r0 = tid >> 2;
    const int c0 = (((tid & 3) ^ ((tid >> 3) & 3)) << 3);
    const uint32_t offA0 = (uint32_t)(rowbase + r0) * lda + c0;
    const uint32_t offB0 = (uint32_t)(colbase + r0) * ldb + c0;
    const uint32_t offB1 = offB0 + (uint32_t)128 * ldb;
    const int dst = tid << 3;

    const int rd_lane = ((lane & 15) << 5) + ((((lane >> 4) ^ (lane >> 1)) & 3) << 3);
    const int wrOff = wr << 11;
    const int wcOff = wc << 11;

#define ISSUE(sv) do { int s_ = (sv); \
    if (s_ < NSTEP) { \
        uint32_t ko_ = (uint32_t)s_ << 5; \
        int slA_ = (s_ & 1) << 12, slB_ = (s_ & 1) << 13; \
        gload_lds16(A  + offA0 + ko_, ldsA + slA_ + dst); \
        gload_lds16(Bt + offB0 + ko_, ldsB + slB_ + dst); \
        gload_lds16(Bt + offB1 + ko_, ldsB + slB_ + dst + 4096); \
    } } while (0)

    f16x8 af[4], bf[4];

#define STEP(sv, slA, slB) { \
    asm volatile("s_waitcnt lgkmcnt(0)" ::: "memory"); \
    __builtin_amdgcn_s_barrier(); \
    asm volatile("" ::: "memory"); \
    ISSUE((sv) + 1); \
    if ((sv) < NSTEP - 1) asm volatile("s_waitcnt vmcnt(3)" ::: "memory"); \
    else                  asm volatile("s_waitcnt vmcnt(0)" ::: "memory"); \
    __builtin_amdgcn_s_barrier(); \
    asm volatile("" ::: "memory"); \
    _Pragma("unroll") for (int mq = 0; mq < 4; ++mq) \
        af[mq] = *(const f16x8*)(ldsA + (slA) + wrOff + (mq << 9) + rd_lane); \
    _Pragma("unroll") for (int n = 0; n < 4; ++n) \
        bf[n] = *(const f16x8*)(ldsB + (slB) + wcOff + (n << 9) + rd_lane); \
    _Pragma("unroll") for (int mq = 0; mq < 4; ++mq) \
    _Pragma("unroll") for (int n = 0; n < 4; ++n) \
        acc[mq][n] = __builtin_amdgcn_mfma_f32_16x16x32_f16(af[mq], bf[n], acc[mq][n], 0, 0, 0); }

    ISSUE(0);
    for (int T = 0; T < NT; ++T) {
        STEP(2 * T,     0,    0)
        STEP(2 * T + 1, 4096, 8192)
    }
#undef STEP
#undef ISSUE
}

// ============ 128x128 fp16 GEMM core (pv): same schedule, 32KB LDS ============
// 8 waves (2Mrow x 4Ncol), per-wave 64x32, acc[4][2].
template<int NT>
__device__ __forceinline__ void gemm_narrow(const u16* __restrict__ A, const u16* __restrict__ Bt,
                                            int lda, int ldb, int rowbase, int colbase,
                                            u16* ldsA, u16* ldsB, f32x4 (&acc)[4][2])
{
    const int NSTEP = 2 * NT;
    const int tid  = threadIdx.x;
    const int lane = tid & 63;
    const int w    = tid >> 6;
    const int wr   = w >> 2, wc = w & 3;

    const int r0 = tid >> 2;
    const int c0 = (((tid & 3) ^ ((tid >> 3) & 3)) << 3);
    const uint32_t offA0 = (uint32_t)(rowbase + r0) * lda + c0;
    const uint32_t offB0 = (uint32_t)(colbase + r0) * ldb + c0;
    const int dst = tid << 3;

    const int rd_lane = ((lane & 15) << 5) + ((((lane >> 4) ^ (lane >> 1)) & 3) << 3);
    const int wrOff = wr << 11;           // wr*64 rows * 32 u16
    const int wcOff = wc << 10;           // wc*32 rows * 32 u16

#define ISSUE(sv) do { int s_ = (sv); \
    if (s_ < NSTEP) { \
        uint32_t ko_ = (uint32_t)s_ << 5; \
        int sl_ = (s_ & 1) << 12; \
        gload_lds16(A  + offA0 + ko_, ldsA + sl_ + dst); \
        gload_lds16(Bt + offB0 + ko_, ldsB + sl_ + dst); \
    } } while (0)

    f16x8 af[4], bf[2];

#define STEP(sv, sl) { \
    asm volatile("s_waitcnt lgkmcnt(0)" ::: "memory"); \
    __builtin_amdgcn_s_barrier(); \
    asm volatile("" ::: "memory"); \
    ISSUE((sv) + 1); \
    if ((sv) < NSTEP - 1) asm volatile("s_waitcnt vmcnt(2)" ::: "memory"); \
    else                  asm volatile("s_waitcnt vmcnt(0)" ::: "memory"); \
    __builtin_amdgcn_s_barrier(); \
    asm volatile("" ::: "memory"); \
    _Pragma("unroll") for (int mq = 0; mq < 4; ++mq) \
        af[mq] = *(const f16x8*)(ldsA + (sl) + wrOff + (mq << 9) + rd_lane); \
    _Pragma("unroll") for (int n = 0; n < 2; ++n) \
        bf[n] = *(const f16x8*)(ldsB + (sl) + wcOff + (n << 9) + rd_lane); \
    _Pragma("unroll") for (int mq = 0; mq < 4; ++mq) \
    _Pragma("unroll") for (int n = 0; n < 2; ++n) \
        acc[mq][n] = __builtin_amdgcn_mfma_f32_16x16x32_f16(af[mq], bf[n], acc[mq][n], 0, 0, 0); }

    ISSUE(0);
    for (int T = 0; T < NT; ++T) {
        STEP(2 * T,     0)
        STEP(2 * T + 1, 4096)
    }
#undef STEP
#undef ISSUE
}

// ---------------- stage 0a: fp32 -> fp16 ----------------
__global__ __launch_bounds__(256) void k_cvt_f16(const float* __restrict__ in,
                                                 u16* __restrict__ oh, int n) {
    int i = (blockIdx.x * 256 + threadIdx.x) << 3;
    if (i >= n) return;
    float4 a = *(const float4*)(in + i);
    float4 b = *(const float4*)(in + i + 4);
    ushort4 h0, h1;
    h0.x = f2h(a.x); h0.y = f2h(a.y); h0.z = f2h(a.z); h0.w = f2h(a.w);
    h1.x = f2h(b.x); h1.y = f2h(b.y); h1.z = f2h(b.z); h1.w = f2h(b.w);
    *(ushort4*)(oh + i)     = h0;
    *(ushort4*)(oh + i + 4) = h1;
}

// ---------------- stage 0b: W [R][C] fp32 -> Wt [C][R] fp16 ----------------
__global__ __launch_bounds__(256) void k_transpose_f16(const float* __restrict__ W,
                                                       u16* __restrict__ Wt, int R, int C) {
    __shared__ float t[32][33];
    int tx = threadIdx.x & 31, ty = threadIdx.x >> 5;
    int c0 = blockIdx.x << 5, r0 = blockIdx.y << 5;
#pragma unroll
    for (int i = 0; i < 4; ++i) {
        int r = (i << 3) + ty;
        t[r][tx] = W[(size_t)(r0 + r) * C + c0 + tx];
    }
    __syncthreads();
#pragma unroll
    for (int i = 0; i < 4; ++i) {
        int r = (i << 3) + ty;
        Wt[(size_t)(c0 + r) * R + r0 + tx] = f2h(t[tx][r]);
    }
}

// ---------------- stage 1: QKV = x @ W + b; store q,k row-major, v transposed ----------------
__global__ __launch_bounds__(512, 4) void k_qkv(const u16* __restrict__ xh,
                                                const u16* __restrict__ wt,
                                                const float* __restrict__ bias,
                                                u16* __restrict__ qf, u16* __restrict__ kf,
                                                u16* __restrict__ vt) {
    __shared__ u16 lds[24576];
    f32x4 acc[4][4];
    f32x4 z = {0.f, 0.f, 0.f, 0.f};
#pragma unroll
    for (int m = 0; m < 4; ++m)
#pragma unroll
        for (int n = 0; n < 4; ++n) acc[m][n] = z;

    const int lid = blockIdx.y * 12 + blockIdx.x;
    const int swz = xcd_swz(lid, 768);
    const int bx = swz % 12, by = swz / 12;
    const int rowbase = by << 7;          // BM = 128
    const int colbase = bx << 8;          // BN = 256
    gemm_wide<16>(xh, wt, D_, D_, rowbase, colbase, lds, lds + 8192, acc);

    const int lane = threadIdx.x & 63;
    const int w = threadIdx.x >> 6;
    const int wr = w >> 2, wc = w & 3;
    const int region = colbase >> 10;     // 0=q, 1=k, 2=v
#pragma unroll
    for (int m = 0; m < 4; ++m) {
        int gr0 = rowbase + wr * 64 + m * 16 + ((lane >> 4) << 2);
#pragma unroll
        for (int n = 0; n < 4; ++n) {
            int gc = colbase + wc * 64 + n * 16 + (lane & 15);
            float bv = bias[gc];
            if (region == 0) {
#pragma unroll
                for (int r = 0; r < 4; ++r)
                    qf[(size_t)(gr0 + r) * D_ + gc] = f2h(acc[m][n][r] + bv);
            } else if (region == 1) {
                int c = gc - 1024;
#pragma unroll
                for (int r = 0; r < 4; ++r)
                    kf[(size_t)(gr0 + r) * D_ + c] = f2h(acc[m][n][r] + bv);
            } else {
                int d  = gc - 2048;
                int b  = gr0 >> 11;
                int t0 = gr0 & 2047;
                size_t base = (((size_t)b << 10) + d) * (size_t)S_ + t0;
#pragma unroll
                for (int r = 0; r < 4; ++r)
                    vt[base + r] = f2h(acc[m][n][r] + bv);
            }
        }
    }
}

// ---------------- stage 2: attn = sigmoid(32 * q @ k^T), fp16 ----------------
__global__ __launch_bounds__(512, 4) void k_scores(const u16* __restrict__ qf,
                                                   const u16* __restrict__ kf,
                                                   u16* __restrict__ attn) {
    __shared__ u16 lds[24576];
    f32x4 acc[4][4];
    f32x4 z = {0.f, 0.f, 0.f, 0.f};
#pragma unroll
    for (int m = 0; m < 4; ++m)
#pragma unroll
        for (int n = 0; n < 4; ++n) acc[m][n] = z;

    const int lid = (blockIdx.z << 7) + (blockIdx.y << 3) + blockIdx.x;
    const int swz = xcd_swz(lid, 512);
    const int bx = swz & 7, by = (swz >> 3) & 15, b = swz >> 7;

    const size_t boff = (size_t)b * S_ * D_;
    u16* att = attn + (size_t)b * S_ * S_;
    const int rowbase = by << 7, colbase = bx << 8;
    gemm_wide<16>(qf + boff, kf + boff, D_, D_, rowbase, colbase, lds, lds + 8192, acc);

    const int lane = threadIdx.x & 63;
    const int w = threadIdx.x >> 6;
    const int wr = w >> 2, wc = w & 3;
#pragma unroll
    for (int m = 0; m < 4; ++m) {
        int gr0 = rowbase + wr * 64 + m * 16 + ((lane >> 4) << 2);
#pragma unroll
        for (int n = 0; n < 4; ++n) {
            int gc = colbase + wc * 64 + n * 16 + (lane & 15);
#pragma unroll
            for (int r = 0; r < 4; ++r) {
                float sv = acc[m][n][r] * 32.0f;
                float sg = 1.0f / (1.0f + __expf(-sv));
                att[(size_t)(gr0 + r) * S_ + gc] = f2h(sg);
            }
        }
    }
}

// ---------------- stage 3: out = attn @ v  (Bt = v^T [D][S]), 128x128 ----------------
__global__ __launch_bounds__(512, 4) void k_pv(const u16* __restrict__ attn,
                                               const u16* __restrict__ vt,
                                               float* __restrict__ out) {
    __shared__ u16 lds[16384];
    f32x4 acc[4][2];
    f32x4 z = {0.f, 0.f, 0.f, 0.f};
#pragma unroll
    for (int m = 0; m < 4; ++m)
#pragma unroll
        for (int n = 0; n < 2; ++n) acc[m][n] = z;

    // swizzle over 8x16x4 = 512 wgs
    const int lid = (blockIdx.z << 7) + (blockIdx.y << 3) + blockIdx.x;
    const int swz = xcd_swz(lid, 512);
    const int bx = swz & 7, by = (swz >> 3) & 15, b = swz >> 7;

    const u16* Aa = attn + (size_t)b * S_ * S_;
    const u16* Bv = vt   + (size_t)b * D_ * S_;
    float* ob     = out  + (size_t)b * S_ * D_;
    const int rowbase = by << 7, colbase = bx << 7;
    gemm_narrow<32>(Aa, Bv, S_, S_, rowbase, colbase, lds, lds + 8192, acc);

    const int lane = threadIdx.x & 63;
    const int w = threadIdx.x >> 6;
    const int wr = w >> 2, wc = w & 3;
#pragma unroll
    for (int m = 0; m < 4; ++m) {
        int gr0 = rowbase + wr * 64 + m * 16 + ((lane >> 4) << 2);
#pragma unroll
        for (int n = 0; n < 2; ++n) {
            int gc = colbase + wc * 32 + n * 16 + (lane & 15);
#pragma unroll
            for (int r = 0; r < 4; ++r)
                ob[(size_t)(gr0 + r) * D_ + gc] = acc[m][n][r];
        }
    }
}

extern "C" void kernel_launch(void* const* d_in, const int* in_sizes, int n_in,
                              void* d_out, int out_size, void* d_ws, size_t ws_size,
                              hipStream_t stream) {
    const float* x    = (const float*)d_in[0];
    const float* wqkv = (const float*)d_in[1];
    const float* bias = (const float*)d_in[2];
    float* out = (float*)d_out;

    const size_t MB = 1048576;
    uint8_t* ws = (uint8_t*)d_ws;
    u16* xh   = (u16*)(ws);              // [8192][1024] f16    16 MB
    u16* wt   = (u16*)(ws + 16 * MB);    // [3072][1024] f16     6 MB
    u16* qf   = (u16*)(ws + 32 * MB);    // [B][S][D] f16       16 MB
    u16* kf   = (u16*)(ws + 48 * MB);    // 16 MB
    u16* vt   = (u16*)(ws + 64 * MB);    // [B][D][S] f16       16 MB (ends 80 MB)
    u16* attn = (u16*)(ws);              // [B][S][S] f16 32 MB — aliases xh/wt (dead after QKV)

    k_cvt_f16<<<dim3(4096), dim3(256), 0, stream>>>(x, xh, B_ * S_ * D_);
    k_transpose_f16<<<dim3(ND3 / 32, D_ / 32), dim3(256), 0, stream>>>(wqkv, wt, D_, ND3);
    k_qkv<<<dim3(ND3 / 256, (B_ * S_) / 128), dim3(512), 0, stream>>>(xh, wt, bias, qf, kf, vt);
    k_scores<<<dim3(S_ / 256, S_ / 128, B_), dim3(512), 0, stream>>>(qf, kf, attn);
    k_pv<<<dim3(D_ / 128, S_ / 128, B_), dim3(512), 0, stream>>>(attn, vt, out);
}